// Round 4
// baseline (332.198 us; speedup 1.0000x reference)
//
#include <hip/hip_runtime.h>
#include <hip/hip_bf16.h>

// Problem constants
constexpr int B_   = 8;
constexpr int D_   = 1024;
constexpr int T_   = 512;
constexpr int HID_ = 256;
constexpr int NH_  = 4;
constexpr int NL_  = 2;
constexpr float ALPHA_ = 0.2f;
constexpr float EPS_   = 1e-5f;
constexpr int OUT_ = 64;
constexpr int M_ = B_ * D_;      // 8192 rows
constexpr int DT_ = D_ * T_;     // 524288
constexpr int KIN_ = 2 * T_;     // 1024
constexpr int CKS_ = 132;        // checkpoint row stride (floats): [0,128)=P1/P2 pairs, [128,130)=scalars

typedef __attribute__((ext_vector_type(8))) short short8;   // 8 bf16 (4 VGPRs)
typedef __attribute__((ext_vector_type(4))) float floatx4;  // 4 fp32 acc

__device__ __forceinline__ unsigned short f2bf(float f) {
    unsigned int u = __float_as_uint(f);
    unsigned int r = u + 0x7fffu + ((u >> 16) & 1u);   // round-to-nearest-even
    return (unsigned short)(r >> 16);
}
__device__ __forceinline__ float bf2f(unsigned short u) {
    return __uint_as_float(((unsigned int)u) << 16);
}
// monotone float<->uint key for atomicMax on signed floats
__device__ __forceinline__ unsigned int kenc(float f) {
    unsigned int u = __float_as_uint(f);
    return (u & 0x80000000u) ? ~u : (u | 0x80000000u);
}
__device__ __forceinline__ float kdec(unsigned int k) {
    unsigned int u = (k & 0x80000000u) ? (k ^ 0x80000000u) : ~k;
    return __uint_as_float(u);
}

// ---------------------------------------------------------------------------
// 1) Fused prep: blocks [0,512): imputation -> Ain bf16 [M][1024]=[X_mean|mask]
//    blocks [512,2560): weight transpose/convert + rmaxkey init
// ---------------------------------------------------------------------------
__global__ __launch_bounds__(256) void prep_k(const float* __restrict__ X,
                                              const float* __restrict__ Mk,
                                              const float* __restrict__ W_in,
                                              const float* __restrict__ gatW,
                                              const float* __restrict__ W_out,
                                              unsigned short* __restrict__ Ain,
                                              unsigned short* __restrict__ Wt_in,
                                              unsigned short* __restrict__ Wcat,
                                              unsigned short* __restrict__ WtO,
                                              unsigned int* __restrict__ rmaxkey) {
    int bx = blockIdx.x;
    if (bx < 512) {
        int idx4 = (bx * 256 + threadIdx.x) * 4;   // over D*T
        int t = idx4 & (T_ - 1);
        int d = idx4 >> 9;
        float4 x[B_], m[B_];
        float4 s = {0, 0, 0, 0}, c = {0, 0, 0, 0};
#pragma unroll
        for (int b = 0; b < B_; b++) {
            x[b] = *(const float4*)&X[(size_t)b * DT_ + idx4];
            m[b] = *(const float4*)&Mk[(size_t)b * DT_ + idx4];
            s.x += x[b].x * m[b].x; s.y += x[b].y * m[b].y;
            s.z += x[b].z * m[b].z; s.w += x[b].w * m[b].w;
            c.x += m[b].x; c.y += m[b].y; c.z += m[b].z; c.w += m[b].w;
        }
        float4 pm;
        pm.x = s.x / (c.x + 1e-10f); pm.y = s.y / (c.y + 1e-10f);
        pm.z = s.z / (c.z + 1e-10f); pm.w = s.w / (c.w + 1e-10f);
#pragma unroll
        for (int b = 0; b < B_; b++) {
            size_t row = (size_t)b * D_ + d;
            ushort4 xm, mk;
            xm.x = f2bf(x[b].x * m[b].x + (1.f - m[b].x) * pm.x);
            xm.y = f2bf(x[b].y * m[b].y + (1.f - m[b].y) * pm.y);
            xm.z = f2bf(x[b].z * m[b].z + (1.f - m[b].z) * pm.z);
            xm.w = f2bf(x[b].w * m[b].w + (1.f - m[b].w) * pm.w);
            mk.x = f2bf(m[b].x); mk.y = f2bf(m[b].y);
            mk.z = f2bf(m[b].z); mk.w = f2bf(m[b].w);
            *(ushort4*)&Ain[row * KIN_ + t]      = xm;
            *(ushort4*)&Ain[row * KIN_ + T_ + t] = mk;
        }
    } else {
        int idx = (bx - 512) * 256 + threadIdx.x;
        if (idx < 64) rmaxkey[idx] = 0u;
        if (idx < 262144) {
            int n = idx >> 10, k = idx & 1023;     // Wt_in[n][k] = W_in[k][n]
            Wt_in[idx] = f2bf(W_in[(size_t)k * HID_ + n]);
        } else if (idx < 393216) {
            int j = idx - 262144;
            int l = j >> 16, n = (j >> 8) & 255, k = j & 255;
            int h = n >> 6, e = n & 63;
            Wcat[j] = f2bf(gatW[(((size_t)(l * NH_ + h) * HID_) + k) * OUT_ + e]);
        } else {
            int j = idx - 393216;
            int n = j >> 8, k = j & 255;           // WtO[n][k] = W_out[k][n]
            WtO[j] = f2bf(W_out[(size_t)k * T_ + n]);
        }
    }
}

// ---------------------------------------------------------------------------
// 2) bf16 MFMA GEMM. BM=128 BN=64 BK=64, 4 waves; wave = 2x(16 rows) x 64 cols.
//    Padded LDS (stride 72); reg-staged ping-pong.
//    MODE 0: fp32 C (+bias). MODE 1: + bf16 copy.
//    MODE 2: hW [bh][m][e] bf16 via LDS-staged coalesced write + s_l/s_r/rmax.
// ---------------------------------------------------------------------------
template <int MODE>
__global__ __launch_bounds__(256) void gemm_bf16_k(
        const unsigned short* __restrict__ A,    // M x K bf16
        const unsigned short* __restrict__ Bt,   // N x K bf16 (B transposed)
        const float* __restrict__ bias,          // N or null (MODE 0/1)
        float* __restrict__ C,                   // M x N fp32 (MODE 0/1)
        unsigned short* __restrict__ Cb,         // bf16 copy (MODE1) / hwN (MODE2)
        const float* __restrict__ ga,            // gat_a + l*512 (MODE2)
        float* __restrict__ s_l,                 // (MODE2)
        float* __restrict__ s_r,                 // (MODE2)
        unsigned int* __restrict__ rmaxkey,      // + l*32 (MODE2)
        int Nsz, int Ksz) {
    __shared__ __align__(16) unsigned short As[2][128 * 72];  // 36.9 KB
    __shared__ __align__(16) unsigned short Bs[2][64 * 72];   // 18.4 KB
    int tid = threadIdx.x;
    int wave = tid >> 6, lane = tid & 63;
    int q = lane >> 4, r16 = lane & 15;
    int rowbase = blockIdx.y * 128;
    int colbase = blockIdx.x * 64;

    int srow = tid >> 3, sk = (tid & 7) * 8;         // staging slot
    const unsigned short* Ap = A + (size_t)(rowbase + srow) * Ksz + sk;
    const unsigned short* Bp = Bt + (size_t)(colbase + srow) * Ksz + sk;
    int la = srow * 72 + sk;

    floatx4 acc[2][4];
#pragma unroll
    for (int mi = 0; mi < 2; mi++)
#pragma unroll
        for (int ni = 0; ni < 4; ni++) acc[mi][ni] = (floatx4)0.f;

    uint4 pa[4], pb[2];
#pragma unroll
    for (int i = 0; i < 4; i++) pa[i] = *(const uint4*)(Ap + (size_t)(i * 32) * Ksz);
#pragma unroll
    for (int i = 0; i < 2; i++) pb[i] = *(const uint4*)(Bp + (size_t)(i * 32) * Ksz);
#pragma unroll
    for (int i = 0; i < 4; i++) *(uint4*)&As[0][la + i * 32 * 72] = pa[i];
#pragma unroll
    for (int i = 0; i < 2; i++) *(uint4*)&Bs[0][la + i * 32 * 72] = pb[i];

    int nk = Ksz >> 6;
    for (int it = 0; it < nk; it++) {
        int cur = it & 1;
        __syncthreads();
        if (it + 1 < nk) {
            int kt = (it + 1) << 6;
#pragma unroll
            for (int i = 0; i < 4; i++) pa[i] = *(const uint4*)(Ap + (size_t)(i * 32) * Ksz + kt);
#pragma unroll
            for (int i = 0; i < 2; i++) pb[i] = *(const uint4*)(Bp + (size_t)(i * 32) * Ksz + kt);
        }
#pragma unroll
        for (int t = 0; t < 2; t++) {
            short8 a0 = *(const short8*)&As[cur][(wave * 16 + r16) * 72 + t * 32 + q * 8];
            short8 a1 = *(const short8*)&As[cur][(64 + wave * 16 + r16) * 72 + t * 32 + q * 8];
#pragma unroll
            for (int ni = 0; ni < 4; ni++) {
                short8 bf = *(const short8*)&Bs[cur][(ni * 16 + r16) * 72 + t * 32 + q * 8];
                acc[0][ni] = __builtin_amdgcn_mfma_f32_16x16x32_bf16(a0, bf, acc[0][ni], 0, 0, 0);
                acc[1][ni] = __builtin_amdgcn_mfma_f32_16x16x32_bf16(a1, bf, acc[1][ni], 0, 0, 0);
            }
        }
        if (it + 1 < nk) {
            int nxt = cur ^ 1;
#pragma unroll
            for (int i = 0; i < 4; i++) *(uint4*)&As[nxt][la + i * 32 * 72] = pa[i];
#pragma unroll
            for (int i = 0; i < 2; i++) *(uint4*)&Bs[nxt][la + i * 32 * 72] = pb[i];
        }
    }
    // ---- epilogue. C/D map: col=lane&15, row=(lane>>4)*4+reg ----
    if constexpr (MODE == 2) {
        int bhh = ((rowbase >> 10) << 2) + blockIdx.x;   // b*4 + h
        int nb0 = rowbase & (D_ - 1);
        // fused s_l/s_r/rmax from fp32 acc
        const float* gab = ga + blockIdx.x * 2 * OUT_;
        float al4[4], ar4[4];
#pragma unroll
        for (int ni = 0; ni < 4; ni++) {
            al4[ni] = gab[ni * 16 + r16];
            ar4[ni] = gab[OUT_ + ni * 16 + r16];
        }
        float mxw = -1e30f;
#pragma unroll
        for (int mi = 0; mi < 2; mi++) {
            float slv[4], srv[4];
#pragma unroll
            for (int rr = 0; rr < 4; rr++) {
                float s1 = 0.f, s2 = 0.f;
#pragma unroll
                for (int ni = 0; ni < 4; ni++) {
                    s1 += acc[mi][ni][rr] * al4[ni];
                    s2 += acc[mi][ni][rr] * ar4[ni];
                }
                slv[rr] = s1;
                srv[rr] = s2;
            }
#pragma unroll
            for (int off = 1; off < 16; off <<= 1) {
#pragma unroll
                for (int rr = 0; rr < 4; rr++) {
                    slv[rr] += __shfl_xor(slv[rr], off, 64);
                    srv[rr] += __shfl_xor(srv[rr], off, 64);
                }
            }
            int rsel = r16 & 3;
            float sv = (rsel == 0) ? slv[0] : (rsel == 1) ? slv[1] : (rsel == 2) ? slv[2] : slv[3];
            float rv = (rsel == 0) ? srv[0] : (rsel == 1) ? srv[1] : (rsel == 2) ? srv[2] : srv[3];
            int n = nb0 + mi * 64 + wave * 16 + q * 4 + rsel;
            if (r16 < 4)                 s_l[bhh * D_ + n] = sv;
            else if (r16 >= 8 && r16 < 12) s_r[bhh * D_ + n] = rv;
            float mx = fmaxf(fmaxf(srv[0], srv[1]), fmaxf(srv[2], srv[3]));
            mxw = fmaxf(mxw, mx);
        }
        mxw = fmaxf(mxw, __shfl_xor(mxw, 16, 64));
        mxw = fmaxf(mxw, __shfl_xor(mxw, 32, 64));
        if (lane == 0) atomicMax(&rmaxkey[bhh], kenc(mxw));
        // hwN tile via LDS (coalesced uint4 rows)
        __syncthreads();
        unsigned short* st = &As[0][0];
#pragma unroll
        for (int mi = 0; mi < 2; mi++)
#pragma unroll
            for (int ni = 0; ni < 4; ni++)
#pragma unroll
                for (int rr = 0; rr < 4; rr++)
                    st[(mi * 64 + wave * 16 + q * 4 + rr) * 72 + ni * 16 + r16] = f2bf(acc[mi][ni][rr]);
        __syncthreads();
#pragma unroll
        for (int i = 0; i < 4; i++) {
            int idx = tid * 4 + i;                 // 128 rows x 8 segs
            int row = idx >> 3, seg = idx & 7;
            uint4 v = *(const uint4*)&st[row * 72 + seg * 8];
            *(uint4*)&Cb[((size_t)bhh << 16) + ((size_t)(nb0 + row) << 6) + seg * 8] = v;
        }
    } else {
#pragma unroll
        for (int mi = 0; mi < 2; mi++)
#pragma unroll
            for (int rr = 0; rr < 4; rr++) {
                int row = rowbase + mi * 64 + wave * 16 + q * 4 + rr;
#pragma unroll
                for (int ni = 0; ni < 4; ni++) {
                    int col = colbase + ni * 16 + r16;
                    float v = acc[mi][ni][rr] + (bias ? bias[col] : 0.f);
                    C[(size_t)row * Nsz + col] = v;
                    if constexpr (MODE == 1) Cb[(size_t)row * Nsz + col] = f2bf(v);
                }
            }
    }
}

// ---------------------------------------------------------------------------
// 3a) rank_k: exact ranking of sr per bh via counting (no sort network).
//     grid (32 bh, 16 segs of 64 elements), 1024 threads.
// ---------------------------------------------------------------------------
__global__ __launch_bounds__(1024) void rank_k(
        const float* __restrict__ sr_g,
        const unsigned int* __restrict__ rmaxkey,
        float* __restrict__ srt,
        int* __restrict__ sig,
        float* __restrict__ wm) {
    __shared__ float skey[1024];
    __shared__ short part[16][64];
    int bh = blockIdx.x, seg = blockIdx.y;
    int tid = threadIdx.x;
    skey[tid] = sr_g[bh * D_ + tid];
    __syncthreads();
    int lane = tid & 63, wv = tid >> 6;
    int el = seg * 64 + lane;
    float k = skey[el];
    int m0 = wv * 64;
    int cnt = 0;
#pragma unroll 4
    for (int m = m0; m < m0 + 64; ++m) {
        float km = skey[m];                       // broadcast
        cnt += (km < k) || (km == k && m < el);   // strict total order
    }
    part[wv][lane] = (short)cnt;
    __syncthreads();
    if (tid < 64) {
        int rank = 0;
#pragma unroll
        for (int w = 0; w < 16; ++w) rank += part[w][tid];
        int elg = seg * 64 + tid;
        float key = skey[elg];
        float rm = kdec(rmaxkey[bh]);
        float u = key - rm;                       // <= 0
        float w1 = __expf(u), w2 = __expf(ALPHA_ * u);
        srt[bh * D_ + rank] = key;
        sig[bh * D_ + rank] = elg;
        *(float2*)&wm[(size_t)(bh * D_ + rank) * 2] = float2{w1, w2};
    }
}

// ---------------------------------------------------------------------------
// 3b) prefix_k: EXCLUSIVE prefix sums of w*V over sorted rank, checkpointed
//     at EVERY rank (streaming writes). 32 blocks x 1024 thr = 16 chunks
//     (wave) x 64 e-lanes, 64 ranks per chunk. ck[bh][t][2e..2e+1]=(P1,P2),
//     [128..129]=(p1s,p2s); ck[bh][1024][*]=totals (same fp chain => exact
//     endpoints at t=0 and t=1024).
// ---------------------------------------------------------------------------
__global__ __launch_bounds__(1024) void prefix_k(
        const unsigned short* __restrict__ hwN,   // [32][1024][64] bf16
        const int* __restrict__ sig,
        const float* __restrict__ wm,
        float* __restrict__ ck) {                 // [32][1025][CKS_]
    __shared__ int   sidx[1024];
    __shared__ float w1s[1024], w2s[1024];
    __shared__ float csum[16][64][2];
    __shared__ float csca[16][2];
    int bh = blockIdx.x, tid = threadIdx.x;
    sidx[tid] = sig[bh * D_ + tid];
    float2 ww = *(const float2*)&wm[(size_t)(bh * D_ + tid) * 2];
    w1s[tid] = ww.x; w2s[tid] = ww.y;
    __syncthreads();
    int e = tid & 63, c = tid >> 6;               // wave = chunk
    const unsigned short* vb = hwN + ((size_t)bh << 16);
    int t0 = c * 64;
    float a1 = 0.f, a2 = 0.f, q1 = 0.f, q2 = 0.f;
    for (int t = t0; t < t0 + 64; ++t) {
        float wv1 = w1s[t], wv2 = w2s[t];
        float v = bf2f(vb[((size_t)sidx[t] << 6) + e]);   // 128B coalesced row
        a1 = fmaf(wv1, v, a1);
        a2 = fmaf(wv2, v, a2);
        q1 += wv1; q2 += wv2;
    }
    csum[c][e][0] = a1; csum[c][e][1] = a2;
    if (e == 0) { csca[c][0] = q1; csca[c][1] = q2; }
    __syncthreads();
    float r1 = 0.f, r2 = 0.f, p1 = 0.f, p2 = 0.f;
    for (int cc = 0; cc < c; ++cc) {
        r1 += csum[cc][e][0]; r2 += csum[cc][e][1];
        p1 += csca[cc][0];    p2 += csca[cc][1];
    }
    float* ckb = ck + (size_t)bh * 1025 * CKS_;
    for (int t = t0; t < t0 + 64; ++t) {
        *(float2*)&ckb[(size_t)t * CKS_ + 2 * e] = float2{r1, r2};
        if (e == 0) *(float2*)&ckb[(size_t)t * CKS_ + 128] = float2{p1, p2};
        float wv1 = w1s[t], wv2 = w2s[t];
        float v = bf2f(vb[((size_t)sidx[t] << 6) + e]);
        r1 = fmaf(wv1, v, r1);
        r2 = fmaf(wv2, v, r2);
        p1 += wv1; p2 += wv2;
    }
    if (c == 15) {   // totals row 1024 (same fp chain => S1(1024)==0 exact)
        *(float2*)&ckb[(size_t)1024 * CKS_ + 2 * e] = float2{r1, r2};
        if (e == 0) *(float2*)&ckb[(size_t)1024 * CKS_ + 128] = float2{p1, p2};
    }
}

// ---------------------------------------------------------------------------
// 4) rowln_k: per (row,head): bsearch -> t, one coalesced ck row load,
//    head_out = fA*(TOT1-P1(t)) + fB*P2(t), then fused residual+LN.
//    Block = 32 rows x 4 heads, 512 threads; phase 1 wave-per-pair. grid 256.
// ---------------------------------------------------------------------------
__global__ __launch_bounds__(512) void rowln_k(
        float* __restrict__ h,                    // hbuf fp32 [M][256], in/out
        const float* __restrict__ sl_g,           // [32][1024]
        const unsigned int* __restrict__ rmaxkey, // +l*32
        const float* __restrict__ srt,
        const float* __restrict__ ck,
        const float* __restrict__ g,
        const float* __restrict__ bb,
        unsigned short* __restrict__ hbf) {
    __shared__ float srtL[4][1024];   // 16 KB
    __shared__ float hnew[32][260];   // 33.3 KB
    __shared__ float ckT1[4][64];     // branch-1 vector totals
    __shared__ float qTs[4][2];
    __shared__ float pdF[128][2];     // fA, fB
    __shared__ int   pdT[128];        // t
    int blk = blockIdx.x;
    int b = blk >> 5;
    int d0 = (blk & 31) << 5;
    int tid = threadIdx.x;
    for (int i = tid; i < 4096; i += 512)
        srtL[i >> 10][i & 1023] = srt[(size_t)((b * 4 + (i >> 10)) * D_) + (i & 1023)];
    if (tid < 256) {
        int hh = tid >> 6, e = tid & 63;
        ckT1[hh][e] = ck[((size_t)((b * 4 + hh) * 1025 + 1024)) * CKS_ + 2 * e];
    }
    if (tid < 8) {
        int hh = tid >> 1;
        qTs[hh][tid & 1] = ck[((size_t)((b * 4 + hh) * 1025 + 1024)) * CKS_ + 128 + (tid & 1)];
    }
    __syncthreads();
    if (tid < 128) {
        int r = tid & 31, h4 = tid >> 5;
        int bh = b * 4 + h4;
        float sl = sl_g[bh * D_ + d0 + r];
        float rm = kdec(rmaxkey[bh]);
        float x = sl + rm;
        float Mn = fmaxf(x, ALPHA_ * x);          // = max_m e[n,m]
        float A  = __expf(x - Mn);
        float B2 = __expf(ALPHA_ * x - Mn);
        float key = -sl;
        int lo = 0, hi = 1024;
        while (lo < hi) {
            int mid = (lo + hi) >> 1;
            if (srtL[h4][mid] < key) lo = mid + 1; else hi = mid;
        }
        float2 qs = *(const float2*)&ck[((size_t)(bh * 1025 + lo)) * CKS_ + 128];
        float den = A * (qTs[h4][0] - qs.x) + B2 * qs.y;
        float inv = 1.f / den;
        pdF[tid][0] = A * inv;
        pdF[tid][1] = B2 * inv;
        pdT[tid] = lo;
    }
    __syncthreads();
    // phase 1: wave-per-pair, lane = e. 16 independent pairs per wave.
    int wv = tid >> 6, e = tid & 63;
    for (int p = wv; p < 128; p += 8) {
        int r = p & 31, h4 = p >> 5;
        int bh = b * 4 + h4;
        float fA = pdF[p][0], fB = pdF[p][1];
        int t = pdT[p];
        float2 P = *(const float2*)&ck[((size_t)(bh * 1025 + t)) * CKS_ + 2 * e];
        hnew[r][h4 * 64 + e] = fA * (ckT1[h4][e] - P.x) + fB * P.y;
    }
    __syncthreads();
    // phase 2: fused residual + LayerNorm, 8 waves x 4 rows
    for (int rr = wv * 4; rr < wv * 4 + 4; ++rr) {
        size_t grow = ((((size_t)b << 10) + d0 + rr) << 8);   // *HID_
        float4 a  = *(const float4*)&h[grow + e * 4];
        float4 nv = *(const float4*)&hnew[rr][e * 4];
        float4 v = {a.x + nv.x, a.y + nv.y, a.z + nv.z, a.w + nv.w};
        float s = v.x + v.y + v.z + v.w;
#pragma unroll
        for (int off = 1; off < 64; off <<= 1) s += __shfl_xor(s, off, 64);
        float mu = s * (1.f / HID_);
        float4 dd = {v.x - mu, v.y - mu, v.z - mu, v.w - mu};
        float s2 = dd.x * dd.x + dd.y * dd.y + dd.z * dd.z + dd.w * dd.w;
#pragma unroll
        for (int off = 1; off < 64; off <<= 1) s2 += __shfl_xor(s2, off, 64);
        float rs = rsqrtf(s2 * (1.f / HID_) + EPS_);
        float4 gg = *(const float4*)&g[e * 4];
        float4 bv = *(const float4*)&bb[e * 4];
        float4 res;
        res.x = dd.x * rs * gg.x + bv.x;
        res.y = dd.y * rs * gg.y + bv.y;
        res.z = dd.z * rs * gg.z + bv.z;
        res.w = dd.w * rs * gg.w + bv.w;
        *(float4*)&h[grow + e * 4] = res;
        ushort4 pk = {f2bf(res.x), f2bf(res.y), f2bf(res.z), f2bf(res.w)};
        *(ushort4*)&hbf[grow + e * 4] = pk;
    }
}

// ---------------------------------------------------------------------------
extern "C" void kernel_launch(void* const* d_in, const int* in_sizes, int n_in,
                              void* d_out, int out_size, void* d_ws, size_t ws_size,
                              hipStream_t stream) {
    const float* X_obs = (const float*)d_in[0];
    const float* mask  = (const float*)d_in[1];
    const float* W_in  = (const float*)d_in[2];
    const float* b_in  = (const float*)d_in[3];
    const float* gat_W = (const float*)d_in[4];
    const float* gat_a = (const float*)d_in[5];
    const float* ln_g  = (const float*)d_in[6];
    const float* ln_b  = (const float*)d_in[7];
    const float* W_out = (const float*)d_in[8];
    const float* b_out = (const float*)d_in[9];
    float* out = (float*)d_out;

    // Workspace layout:
    //  [0,16M):   Ain bf16 (M x 1024), dead after gemm1; then:
    //             hwN bf16 [32][1024][64] at [0,4M)
    //  [4M,20.6M): ck fp32 [32][1025][132] (~16.5 MB)
    //  [22M):     wm (256K)  [22.5M): srt (128K)  [22.75M): sig (128K)
    //  [23M,31M): hbuf fp32 (M x 256)
    //  [31M,35M): hbf bf16 (M x 256)
    //  [35M,+):   Wt_in, Wcat, WtO (bf16), slb/srb (fp32), rmaxkey (uint[64])
    char* base = (char*)d_ws;
    unsigned short* Ain = (unsigned short*)base;
    unsigned short* hwN = (unsigned short*)base;
    float* ck   = (float*)(base + (4u << 20));
    float* wm   = (float*)(base + (22u << 20));
    float* srtb = (float*)(base + (22u << 20) + (512u << 10));
    int*   sig  = (int*)(base + (22u << 20) + (768u << 10));
    float* hbuf = (float*)(base + (23u << 20));
    unsigned short* hbf   = (unsigned short*)(base + (31u << 20));
    unsigned short* Wt_in = (unsigned short*)(base + (35u << 20));
    unsigned short* Wcat  = Wt_in + (size_t)HID_ * KIN_;        // 256*1024
    unsigned short* WtO   = Wcat + (size_t)NL_ * HID_ * HID_;   // 2*256*256
    float* slb = (float*)(WtO + (size_t)T_ * HID_);             // 32*1024
    float* srb = slb + B_ * NH_ * D_;
    unsigned int* rmaxkey = (unsigned int*)(srb + B_ * NH_ * D_);  // [2][32]

    prep_k<<<2560, 256, 0, stream>>>(X_obs, mask, W_in, gat_W, W_out,
                                     Ain, Wt_in, Wcat, WtO, rmaxkey);

    // h = [X_mean|mask] @ W_in + b_in   (8192x1024)@(1024x256), fp32+bf16 out
    gemm_bf16_k<1><<<dim3(HID_ / 64, M_ / 128), 256, 0, stream>>>(
        Ain, Wt_in, b_in, hbuf, hbf, nullptr, nullptr, nullptr, nullptr,
        HID_, KIN_);

    for (int l = 0; l < NL_; l++) {
        // hW = h @ Wcat[l] -> hwN [bh][m][e] bf16 + fused s_l/s_r/rmax
        gemm_bf16_k<2><<<dim3(HID_ / 64, M_ / 128), 256, 0, stream>>>(
            hbf, Wcat + (size_t)l * HID_ * HID_, nullptr, nullptr, hwN,
            gat_a + (size_t)l * NH_ * 2 * OUT_, slb, srb, rmaxkey + l * 32,
            HID_, HID_);
        // exact rank of sr per bh (counting, whole-GPU parallel)
        rank_k<<<dim3(32, 16), 1024, 0, stream>>>(srb, rmaxkey + l * 32,
                                                  srtb, sig, wm);
        // full-resolution weighted prefix checkpoints over sorted rank
        prefix_k<<<32, 1024, 0, stream>>>(hwN, sig, wm, ck);
        // per-row gather + residual + LayerNorm
        rowln_k<<<256, 512, 0, stream>>>(hbuf, slb, rmaxkey + l * 32,
                                         srtb, ck,
                                         ln_g + (size_t)l * HID_,
                                         ln_b + (size_t)l * HID_, hbf);
    }

    // out = h @ W_out + b_out  (8192x256)@(256x512), fp32 out
    gemm_bf16_k<0><<<dim3(T_ / 64, M_ / 128), 256, 0, stream>>>(
        hbf, WtO, b_out, out, nullptr, nullptr, nullptr, nullptr, nullptr,
        T_, HID_);
}

// Round 5
// 249.200 us; speedup vs baseline: 1.3331x; 1.3331x over previous
//
#include <hip/hip_runtime.h>
#include <hip/hip_bf16.h>

// Problem constants
constexpr int B_   = 8;
constexpr int D_   = 1024;
constexpr int T_   = 512;
constexpr int HID_ = 256;
constexpr int NH_  = 4;
constexpr int NL_  = 2;
constexpr float ALPHA_ = 0.2f;
constexpr float EPS_   = 1e-5f;
constexpr int OUT_ = 64;
constexpr int M_ = B_ * D_;      // 8192 rows
constexpr int DT_ = D_ * T_;     // 524288
constexpr int KIN_ = 2 * T_;     // 1024
constexpr int CKS_ = 132;        // checkpoint row stride (floats): [0,128)=P1/P2 pairs, [128,130)=scalars
constexpr int NCH_ = 32;         // prefix chunks per bh
constexpr int CR_  = 32;         // ranks per chunk

typedef __attribute__((ext_vector_type(8))) short short8;   // 8 bf16 (4 VGPRs)
typedef __attribute__((ext_vector_type(4))) float floatx4;  // 4 fp32 acc

__device__ __forceinline__ unsigned short f2bf(float f) {
    unsigned int u = __float_as_uint(f);
    unsigned int r = u + 0x7fffu + ((u >> 16) & 1u);   // round-to-nearest-even
    return (unsigned short)(r >> 16);
}
__device__ __forceinline__ float bf2f(unsigned short u) {
    return __uint_as_float(((unsigned int)u) << 16);
}
// monotone float<->uint key for atomicMax on signed floats
__device__ __forceinline__ unsigned int kenc(float f) {
    unsigned int u = __float_as_uint(f);
    return (u & 0x80000000u) ? ~u : (u | 0x80000000u);
}
__device__ __forceinline__ float kdec(unsigned int k) {
    unsigned int u = (k & 0x80000000u) ? (k ^ 0x80000000u) : ~k;
    return __uint_as_float(u);
}

// ---------------------------------------------------------------------------
// 1) Fused prep: blocks [0,512): imputation -> Ain bf16 [M][1024]=[X_mean|mask]
//    blocks [512,2560): weight transpose/convert + rmaxkey init
// ---------------------------------------------------------------------------
__global__ __launch_bounds__(256) void prep_k(const float* __restrict__ X,
                                              const float* __restrict__ Mk,
                                              const float* __restrict__ W_in,
                                              const float* __restrict__ gatW,
                                              const float* __restrict__ W_out,
                                              unsigned short* __restrict__ Ain,
                                              unsigned short* __restrict__ Wt_in,
                                              unsigned short* __restrict__ Wcat,
                                              unsigned short* __restrict__ WtO,
                                              unsigned int* __restrict__ rmaxkey) {
    int bx = blockIdx.x;
    if (bx < 512) {
        int idx4 = (bx * 256 + threadIdx.x) * 4;   // over D*T
        int t = idx4 & (T_ - 1);
        int d = idx4 >> 9;
        float4 x[B_], m[B_];
        float4 s = {0, 0, 0, 0}, c = {0, 0, 0, 0};
#pragma unroll
        for (int b = 0; b < B_; b++) {
            x[b] = *(const float4*)&X[(size_t)b * DT_ + idx4];
            m[b] = *(const float4*)&Mk[(size_t)b * DT_ + idx4];
            s.x += x[b].x * m[b].x; s.y += x[b].y * m[b].y;
            s.z += x[b].z * m[b].z; s.w += x[b].w * m[b].w;
            c.x += m[b].x; c.y += m[b].y; c.z += m[b].z; c.w += m[b].w;
        }
        float4 pm;
        pm.x = s.x / (c.x + 1e-10f); pm.y = s.y / (c.y + 1e-10f);
        pm.z = s.z / (c.z + 1e-10f); pm.w = s.w / (c.w + 1e-10f);
#pragma unroll
        for (int b = 0; b < B_; b++) {
            size_t row = (size_t)b * D_ + d;
            ushort4 xm, mk;
            xm.x = f2bf(x[b].x * m[b].x + (1.f - m[b].x) * pm.x);
            xm.y = f2bf(x[b].y * m[b].y + (1.f - m[b].y) * pm.y);
            xm.z = f2bf(x[b].z * m[b].z + (1.f - m[b].z) * pm.z);
            xm.w = f2bf(x[b].w * m[b].w + (1.f - m[b].w) * pm.w);
            mk.x = f2bf(m[b].x); mk.y = f2bf(m[b].y);
            mk.z = f2bf(m[b].z); mk.w = f2bf(m[b].w);
            *(ushort4*)&Ain[row * KIN_ + t]      = xm;
            *(ushort4*)&Ain[row * KIN_ + T_ + t] = mk;
        }
    } else {
        int idx = (bx - 512) * 256 + threadIdx.x;
        if (idx < 64) rmaxkey[idx] = 0u;
        if (idx < 262144) {
            int n = idx >> 10, k = idx & 1023;     // Wt_in[n][k] = W_in[k][n]
            Wt_in[idx] = f2bf(W_in[(size_t)k * HID_ + n]);
        } else if (idx < 393216) {
            int j = idx - 262144;
            int l = j >> 16, n = (j >> 8) & 255, k = j & 255;
            int h = n >> 6, e = n & 63;
            Wcat[j] = f2bf(gatW[(((size_t)(l * NH_ + h) * HID_) + k) * OUT_ + e]);
        } else {
            int j = idx - 393216;
            int n = j >> 8, k = j & 255;           // WtO[n][k] = W_out[k][n]
            WtO[j] = f2bf(W_out[(size_t)k * T_ + n]);
        }
    }
}

// ---------------------------------------------------------------------------
// 2) bf16 MFMA GEMM. BM=64 BN=64 BK=64, 4 waves, wave = 16 rows x 64 cols.
//    Padded LDS (stride 72); reg-staged ping-pong. Grid 512 -> 2 blocks/CU.
//    MODE 0: fp32 C (+bias). MODE 1: + bf16 copy.
//    MODE 2: hW [bh][m][e] bf16 via LDS-staged coalesced write + s_l/s_r/rmax.
// ---------------------------------------------------------------------------
template <int MODE>
__global__ __launch_bounds__(256) void gemm_bf16_k(
        const unsigned short* __restrict__ A,    // M x K bf16
        const unsigned short* __restrict__ Bt,   // N x K bf16 (B transposed)
        const float* __restrict__ bias,          // N or null (MODE 0/1)
        float* __restrict__ C,                   // M x N fp32 (MODE 0/1)
        unsigned short* __restrict__ Cb,         // bf16 copy (MODE1) / hwN (MODE2)
        const float* __restrict__ ga,            // gat_a + l*512 (MODE2)
        float* __restrict__ s_l,                 // (MODE2)
        float* __restrict__ s_r,                 // (MODE2)
        unsigned int* __restrict__ rmaxkey,      // + l*32 (MODE2)
        int Nsz, int Ksz) {
    __shared__ __align__(16) unsigned short As[2][64 * 72];  // 18 KB, padded
    __shared__ __align__(16) unsigned short Bs[2][64 * 72];  // 18 KB
    int tid = threadIdx.x;
    int wave = tid >> 6, lane = tid & 63;
    int q = lane >> 4, r16 = lane & 15;
    int rowbase = blockIdx.y * 64;
    int colbase = blockIdx.x * 64;

    int srow = tid >> 3, sk = (tid & 7) * 8;         // staging slot
    const unsigned short* Ap0 = A + (size_t)(rowbase + srow) * Ksz + sk;
    const unsigned short* Ap1 = A + (size_t)(rowbase + srow + 32) * Ksz + sk;
    const unsigned short* Bp0 = Bt + (size_t)(colbase + srow) * Ksz + sk;
    const unsigned short* Bp1 = Bt + (size_t)(colbase + srow + 32) * Ksz + sk;
    int la0 = srow * 72 + sk, la1 = (srow + 32) * 72 + sk;

    floatx4 acc[4];
#pragma unroll
    for (int i = 0; i < 4; i++) acc[i] = (floatx4)0.f;

    uint4 pa0 = *(const uint4*)Ap0, pa1 = *(const uint4*)Ap1;
    uint4 pb0 = *(const uint4*)Bp0, pb1 = *(const uint4*)Bp1;
    *(uint4*)&As[0][la0] = pa0;
    *(uint4*)&As[0][la1] = pa1;
    *(uint4*)&Bs[0][la0] = pb0;
    *(uint4*)&Bs[0][la1] = pb1;

    int nk = Ksz >> 6;
    for (int it = 0; it < nk; it++) {
        int cur = it & 1;
        __syncthreads();
        if (it + 1 < nk) {
            int kt = (it + 1) << 6;
            pa0 = *(const uint4*)(Ap0 + kt);
            pa1 = *(const uint4*)(Ap1 + kt);
            pb0 = *(const uint4*)(Bp0 + kt);
            pb1 = *(const uint4*)(Bp1 + kt);
        }
#pragma unroll
        for (int t = 0; t < 2; t++) {
            short8 a = *(const short8*)&As[cur][(wave * 16 + r16) * 72 + t * 32 + q * 8];
#pragma unroll
            for (int ni = 0; ni < 4; ni++) {
                short8 b = *(const short8*)&Bs[cur][(ni * 16 + r16) * 72 + t * 32 + q * 8];
                acc[ni] = __builtin_amdgcn_mfma_f32_16x16x32_bf16(a, b, acc[ni], 0, 0, 0);
            }
        }
        if (it + 1 < nk) {
            int nxt = cur ^ 1;
            *(uint4*)&As[nxt][la0] = pa0;
            *(uint4*)&As[nxt][la1] = pa1;
            *(uint4*)&Bs[nxt][la0] = pb0;
            *(uint4*)&Bs[nxt][la1] = pb1;
        }
    }
    // ---- epilogue. C/D map: col=lane&15, row=(lane>>4)*4+reg ----
    if constexpr (MODE == 2) {
        int bhh = ((rowbase >> 10) << 2) + blockIdx.x;   // b*4 + h
        int nb0 = rowbase & (D_ - 1);
        int nb = nb0 + wave * 16;
        // fused s_l/s_r from fp32 acc
        const float* gab = ga + blockIdx.x * 2 * OUT_;
        float al4[4], ar4[4];
#pragma unroll
        for (int ni = 0; ni < 4; ni++) {
            al4[ni] = gab[ni * 16 + r16];
            ar4[ni] = gab[OUT_ + ni * 16 + r16];
        }
        float slv[4], srv[4];
#pragma unroll
        for (int rr = 0; rr < 4; rr++) {
            float s1 = 0.f, s2 = 0.f;
#pragma unroll
            for (int ni = 0; ni < 4; ni++) {
                s1 += acc[ni][rr] * al4[ni];
                s2 += acc[ni][rr] * ar4[ni];
            }
            slv[rr] = s1;
            srv[rr] = s2;
        }
#pragma unroll
        for (int off = 1; off < 16; off <<= 1) {
#pragma unroll
            for (int rr = 0; rr < 4; rr++) {
                slv[rr] += __shfl_xor(slv[rr], off, 64);
                srv[rr] += __shfl_xor(srv[rr], off, 64);
            }
        }
        {
            int rsel = r16 & 3;
            float sv = (rsel == 0) ? slv[0] : (rsel == 1) ? slv[1] : (rsel == 2) ? slv[2] : slv[3];
            float rv = (rsel == 0) ? srv[0] : (rsel == 1) ? srv[1] : (rsel == 2) ? srv[2] : srv[3];
            int n = nb + q * 4 + rsel;
            if (r16 < 4)                 s_l[bhh * D_ + n] = sv;
            else if (r16 >= 8 && r16 < 12) s_r[bhh * D_ + n] = rv;
        }
        float mx = fmaxf(fmaxf(srv[0], srv[1]), fmaxf(srv[2], srv[3]));
        mx = fmaxf(mx, __shfl_xor(mx, 16, 64));
        mx = fmaxf(mx, __shfl_xor(mx, 32, 64));
        if (lane == 0) atomicMax(&rmaxkey[bhh], kenc(mx));
        // hwN tile via LDS staging -> coalesced uint4 rows
        __syncthreads();
        unsigned short* st = &As[0][0];
#pragma unroll
        for (int ni = 0; ni < 4; ni++)
#pragma unroll
            for (int rr = 0; rr < 4; rr++)
                st[(wave * 16 + q * 4 + rr) * 72 + ni * 16 + r16] = f2bf(acc[ni][rr]);
        __syncthreads();
#pragma unroll
        for (int i = 0; i < 2; i++) {
            int idx = tid * 2 + i;                 // 64 rows x 8 segs
            int row = idx >> 3, seg = idx & 7;
            uint4 v = *(const uint4*)&st[row * 72 + seg * 8];
            *(uint4*)&Cb[((size_t)bhh << 16) + ((size_t)(nb0 + row) << 6) + seg * 8] = v;
        }
    } else {
#pragma unroll
        for (int rr = 0; rr < 4; rr++) {
            int row = rowbase + wave * 16 + q * 4 + rr;
#pragma unroll
            for (int ni = 0; ni < 4; ni++) {
                int col = colbase + ni * 16 + r16;
                float v = acc[ni][rr] + (bias ? bias[col] : 0.f);
                C[(size_t)row * Nsz + col] = v;
                if constexpr (MODE == 1) Cb[(size_t)row * Nsz + col] = f2bf(v);
            }
        }
    }
}

// ---------------------------------------------------------------------------
// 3a) rank_k: exact ranking of sr per bh via counting (no sort network).
//     grid (32 bh, 16 segs of 64 elements), 1024 threads.
// ---------------------------------------------------------------------------
__global__ __launch_bounds__(1024) void rank_k(
        const float* __restrict__ sr_g,
        const unsigned int* __restrict__ rmaxkey,
        float* __restrict__ srt,
        int* __restrict__ sig,
        float* __restrict__ wm) {
    __shared__ float skey[1024];
    __shared__ short part[16][64];
    int bh = blockIdx.x, seg = blockIdx.y;
    int tid = threadIdx.x;
    skey[tid] = sr_g[bh * D_ + tid];
    __syncthreads();
    int lane = tid & 63, wv = tid >> 6;
    int el = seg * 64 + lane;
    float k = skey[el];
    int m0 = wv * 64;
    int cnt = 0;
#pragma unroll 4
    for (int m = m0; m < m0 + 64; ++m) {
        float km = skey[m];                       // broadcast
        cnt += (km < k) || (km == k && m < el);   // strict total order
    }
    part[wv][lane] = (short)cnt;
    __syncthreads();
    if (tid < 64) {
        int rank = 0;
#pragma unroll
        for (int w = 0; w < 16; ++w) rank += part[w][tid];
        int elg = seg * 64 + tid;
        float key = skey[elg];
        float rm = kdec(rmaxkey[bh]);
        float u = key - rm;                       // <= 0
        float w1 = __expf(u), w2 = __expf(ALPHA_ * u);
        srt[bh * D_ + rank] = key;
        sig[bh * D_ + rank] = elg;
        *(float2*)&wm[(size_t)(bh * D_ + rank) * 2] = float2{w1, w2};
    }
}

// ---------------------------------------------------------------------------
// 3b) chunksum_k: per-chunk sums of w*V over sorted rank. grid (32 bh,
//     32 chunks of 32 ranks), 64 threads (lane = e). Coalesced 128B gathers.
// ---------------------------------------------------------------------------
__global__ __launch_bounds__(64) void chunksum_k(
        const unsigned short* __restrict__ hwN,   // [32][1024][64] bf16
        const int* __restrict__ sig,
        const float* __restrict__ wm,
        float* __restrict__ csum,                 // [32][32][64][2]
        float* __restrict__ csca) {               // [32][32][2]
    int bh = blockIdx.x, c = blockIdx.y;
    int e = threadIdx.x;
    const unsigned short* vb = hwN + ((size_t)bh << 16);
    int t0 = c * CR_;
    float a1 = 0.f, a2 = 0.f, q1 = 0.f, q2 = 0.f;
#pragma unroll 4
    for (int t = t0; t < t0 + CR_; ++t) {
        float2 ww = *(const float2*)&wm[(size_t)(bh * D_ + t) * 2];
        float v = bf2f(vb[((size_t)sig[bh * D_ + t] << 6) + e]);
        a1 = fmaf(ww.x, v, a1);
        a2 = fmaf(ww.y, v, a2);
        q1 += ww.x; q2 += ww.y;
    }
    *(float2*)&csum[(((size_t)bh * NCH_ + c) * 64 + e) * 2] = float2{a1, a2};
    if (e == 0) *(float2*)&csca[((size_t)bh * NCH_ + c) * 2] = float2{q1, q2};
}

// ---------------------------------------------------------------------------
// 3c) ckwrite_k: reduce chunk offsets, then stream EXCLUSIVE prefix
//     checkpoints for this chunk's 32 ranks. grid (32, 32), 64 threads.
//     Row 1024 (totals) written by c=31 from the same fp chain, and it IS
//     the t=1024 checkpoint => S1(1024) == 0 exact; row 0 offset == 0 exact.
// ---------------------------------------------------------------------------
__global__ __launch_bounds__(64) void ckwrite_k(
        const unsigned short* __restrict__ hwN,
        const int* __restrict__ sig,
        const float* __restrict__ wm,
        const float* __restrict__ csum,
        const float* __restrict__ csca,
        float* __restrict__ ck) {                 // [32][1025][CKS_]
    int bh = blockIdx.x, c = blockIdx.y;
    int e = threadIdx.x;
    float r1 = 0.f, r2 = 0.f, p1 = 0.f, p2 = 0.f;
    for (int cc = 0; cc < c; ++cc) {
        float2 s  = *(const float2*)&csum[(((size_t)bh * NCH_ + cc) * 64 + e) * 2];
        float2 sc = *(const float2*)&csca[((size_t)bh * NCH_ + cc) * 2];
        r1 += s.x; r2 += s.y;
        p1 += sc.x; p2 += sc.y;
    }
    const unsigned short* vb = hwN + ((size_t)bh << 16);
    float* ckb = ck + (size_t)bh * 1025 * CKS_;
    int t0 = c * CR_;
    for (int t = t0; t < t0 + CR_; ++t) {
        *(float2*)&ckb[(size_t)t * CKS_ + 2 * e] = float2{r1, r2};
        if (e == 0) *(float2*)&ckb[(size_t)t * CKS_ + 128] = float2{p1, p2};
        float2 ww = *(const float2*)&wm[(size_t)(bh * D_ + t) * 2];
        float v = bf2f(vb[((size_t)sig[bh * D_ + t] << 6) + e]);
        r1 = fmaf(ww.x, v, r1);
        r2 = fmaf(ww.y, v, r2);
        p1 += ww.x; p2 += ww.y;
    }
    if (c == NCH_ - 1) {
        *(float2*)&ckb[(size_t)1024 * CKS_ + 2 * e] = float2{r1, r2};
        if (e == 0) *(float2*)&ckb[(size_t)1024 * CKS_ + 128] = float2{p1, p2};
    }
}

// ---------------------------------------------------------------------------
// 4) rowln_k: per (row,head): bsearch -> t, one coalesced ck row load,
//    head_out = fA*(TOT1-P1(t)) + fB*P2(t), then fused residual+LN.
//    Block = 32 rows x 4 heads, 512 threads; phase 1 wave-per-pair. grid 256.
// ---------------------------------------------------------------------------
__global__ __launch_bounds__(512) void rowln_k(
        float* __restrict__ h,                    // hbuf fp32 [M][256], in/out
        const float* __restrict__ sl_g,           // [32][1024]
        const unsigned int* __restrict__ rmaxkey, // +l*32
        const float* __restrict__ srt,
        const float* __restrict__ ck,
        const float* __restrict__ g,
        const float* __restrict__ bb,
        unsigned short* __restrict__ hbf) {
    __shared__ float srtL[4][1024];   // 16 KB
    __shared__ float hnew[32][260];   // 33.3 KB
    __shared__ float ckT1[4][64];     // branch-1 vector totals
    __shared__ float qTs[4][2];
    __shared__ float pdF[128][2];     // fA, fB
    __shared__ int   pdT[128];        // t
    int blk = blockIdx.x;
    int b = blk >> 5;
    int d0 = (blk & 31) << 5;
    int tid = threadIdx.x;
    for (int i = tid; i < 4096; i += 512)
        srtL[i >> 10][i & 1023] = srt[(size_t)((b * 4 + (i >> 10)) * D_) + (i & 1023)];
    if (tid < 256) {
        int hh = tid >> 6, e = tid & 63;
        ckT1[hh][e] = ck[((size_t)((b * 4 + hh) * 1025 + 1024)) * CKS_ + 2 * e];
    }
    if (tid < 8) {
        int hh = tid >> 1;
        qTs[hh][tid & 1] = ck[((size_t)((b * 4 + hh) * 1025 + 1024)) * CKS_ + 128 + (tid & 1)];
    }
    __syncthreads();
    if (tid < 128) {
        int r = tid & 31, h4 = tid >> 5;
        int bh = b * 4 + h4;
        float sl = sl_g[bh * D_ + d0 + r];
        float rm = kdec(rmaxkey[bh]);
        float x = sl + rm;
        float Mn = fmaxf(x, ALPHA_ * x);          // = max_m e[n,m]
        float A  = __expf(x - Mn);
        float B2 = __expf(ALPHA_ * x - Mn);
        float key = -sl;
        int lo = 0, hi = 1024;
        while (lo < hi) {
            int mid = (lo + hi) >> 1;
            if (srtL[h4][mid] < key) lo = mid + 1; else hi = mid;
        }
        float2 qs = *(const float2*)&ck[((size_t)(bh * 1025 + lo)) * CKS_ + 128];
        float den = A * (qTs[h4][0] - qs.x) + B2 * qs.y;
        float inv = 1.f / den;
        pdF[tid][0] = A * inv;
        pdF[tid][1] = B2 * inv;
        pdT[tid] = lo;
    }
    __syncthreads();
    // phase 1: wave-per-pair, lane = e. 16 independent pairs per wave.
    int wv = tid >> 6, e = tid & 63;
    for (int p = wv; p < 128; p += 8) {
        int r = p & 31, h4 = p >> 5;
        int bh = b * 4 + h4;
        float fA = pdF[p][0], fB = pdF[p][1];
        int t = pdT[p];
        float2 P = *(const float2*)&ck[((size_t)(bh * 1025 + t)) * CKS_ + 2 * e];
        hnew[r][h4 * 64 + e] = fA * (ckT1[h4][e] - P.x) + fB * P.y;
    }
    __syncthreads();
    // phase 2: fused residual + LayerNorm, 8 waves x 4 rows
    for (int rr = wv * 4; rr < wv * 4 + 4; ++rr) {
        size_t grow = ((((size_t)b << 10) + d0 + rr) << 8);   // *HID_
        float4 a  = *(const float4*)&h[grow + e * 4];
        float4 nv = *(const float4*)&hnew[rr][e * 4];
        float4 v = {a.x + nv.x, a.y + nv.y, a.z + nv.z, a.w + nv.w};
        float s = v.x + v.y + v.z + v.w;
#pragma unroll
        for (int off = 1; off < 64; off <<= 1) s += __shfl_xor(s, off, 64);
        float mu = s * (1.f / HID_);
        float4 dd = {v.x - mu, v.y - mu, v.z - mu, v.w - mu};
        float s2 = dd.x * dd.x + dd.y * dd.y + dd.z * dd.z + dd.w * dd.w;
#pragma unroll
        for (int off = 1; off < 64; off <<= 1) s2 += __shfl_xor(s2, off, 64);
        float rs = rsqrtf(s2 * (1.f / HID_) + EPS_);
        float4 gg = *(const float4*)&g[e * 4];
        float4 bv = *(const float4*)&bb[e * 4];
        float4 res;
        res.x = dd.x * rs * gg.x + bv.x;
        res.y = dd.y * rs * gg.y + bv.y;
        res.z = dd.z * rs * gg.z + bv.z;
        res.w = dd.w * rs * gg.w + bv.w;
        *(float4*)&h[grow + e * 4] = res;
        ushort4 pk = {f2bf(res.x), f2bf(res.y), f2bf(res.z), f2bf(res.w)};
        *(ushort4*)&hbf[grow + e * 4] = pk;
    }
}

// ---------------------------------------------------------------------------
extern "C" void kernel_launch(void* const* d_in, const int* in_sizes, int n_in,
                              void* d_out, int out_size, void* d_ws, size_t ws_size,
                              hipStream_t stream) {
    const float* X_obs = (const float*)d_in[0];
    const float* mask  = (const float*)d_in[1];
    const float* W_in  = (const float*)d_in[2];
    const float* b_in  = (const float*)d_in[3];
    const float* gat_W = (const float*)d_in[4];
    const float* gat_a = (const float*)d_in[5];
    const float* ln_g  = (const float*)d_in[6];
    const float* ln_b  = (const float*)d_in[7];
    const float* W_out = (const float*)d_in[8];
    const float* b_out = (const float*)d_in[9];
    float* out = (float*)d_out;

    // Workspace layout:
    //  [0,16M):   Ain bf16 (M x 1024), dead after gemm1; then:
    //             hwN bf16 [32][1024][64] at [0,4M)
    //  [4M,20.6M): ck fp32 [32][1025][132] (~16.5 MB)
    //  [21M):     csum (512K) + csca (8K)
    //  [22M):     wm (256K)  [22.5M): srt (128K)  [22.75M): sig (128K)
    //  [23M,31M): hbuf fp32 (M x 256)
    //  [31M,35M): hbf bf16 (M x 256)
    //  [35M,+):   Wt_in, Wcat, WtO (bf16), slb/srb (fp32), rmaxkey (uint[64])
    char* base = (char*)d_ws;
    unsigned short* Ain = (unsigned short*)base;
    unsigned short* hwN = (unsigned short*)base;
    float* ck   = (float*)(base + (4u << 20));
    float* csum = (float*)(base + (21u << 20));
    float* csca = (float*)(base + (21u << 20) + (512u << 10));
    float* wm   = (float*)(base + (22u << 20));
    float* srtb = (float*)(base + (22u << 20) + (512u << 10));
    int*   sig  = (int*)(base + (22u << 20) + (768u << 10));
    float* hbuf = (float*)(base + (23u << 20));
    unsigned short* hbf   = (unsigned short*)(base + (31u << 20));
    unsigned short* Wt_in = (unsigned short*)(base + (35u << 20));
    unsigned short* Wcat  = Wt_in + (size_t)HID_ * KIN_;        // 256*1024
    unsigned short* WtO   = Wcat + (size_t)NL_ * HID_ * HID_;   // 2*256*256
    float* slb = (float*)(WtO + (size_t)T_ * HID_);             // 32*1024
    float* srb = slb + B_ * NH_ * D_;
    unsigned int* rmaxkey = (unsigned int*)(srb + B_ * NH_ * D_);  // [2][32]

    prep_k<<<2560, 256, 0, stream>>>(X_obs, mask, W_in, gat_W, W_out,
                                     Ain, Wt_in, Wcat, WtO, rmaxkey);

    // h = [X_mean|mask] @ W_in + b_in   (8192x1024)@(1024x256), fp32+bf16 out
    gemm_bf16_k<1><<<dim3(HID_ / 64, M_ / 64), 256, 0, stream>>>(
        Ain, Wt_in, b_in, hbuf, hbf, nullptr, nullptr, nullptr, nullptr,
        HID_, KIN_);

    for (int l = 0; l < NL_; l++) {
        // hW = h @ Wcat[l] -> hwN [bh][m][e] bf16 + fused s_l/s_r/rmax
        gemm_bf16_k<2><<<dim3(HID_ / 64, M_ / 64), 256, 0, stream>>>(
            hbf, Wcat + (size_t)l * HID_ * HID_, nullptr, nullptr, hwN,
            gat_a + (size_t)l * NH_ * 2 * OUT_, slb, srb, rmaxkey + l * 32,
            HID_, HID_);
        // exact rank of sr per bh (counting, whole-GPU parallel)
        rank_k<<<dim3(32, 16), 1024, 0, stream>>>(srb, rmaxkey + l * 32,
                                                  srtb, sig, wm);
        // per-chunk sums, then wide streaming prefix-checkpoint writes
        chunksum_k<<<dim3(32, NCH_), 64, 0, stream>>>(hwN, sig, wm, csum, csca);
        ckwrite_k<<<dim3(32, NCH_), 64, 0, stream>>>(hwN, sig, wm, csum, csca, ck);
        // per-row gather + residual + LayerNorm
        rowln_k<<<256, 512, 0, stream>>>(hbuf, slb, rmaxkey + l * 32,
                                         srtb, ck,
                                         ln_g + (size_t)l * HID_,
                                         ln_b + (size_t)l * HID_, hbf);
    }

    // out = h @ W_out + b_out  (8192x256)@(256x512), fp32 out
    gemm_bf16_k<0><<<dim3(T_ / 64, M_ / 64), 256, 0, stream>>>(
        hbf, WtO, b_out, out, nullptr, nullptr, nullptr, nullptr, nullptr,
        T_, HID_);
}